// Round 3
// baseline (1021.681 us; speedup 1.0000x reference)
//
#include <hip/hip_runtime.h>

// SparseConv2D on MI355X (gfx950), round 3.
// Collapsed valid 3x3 conv:
//   out[n,r,c,co] = active[n,r/14,c/14] * (bias[co] +
//       sum_{dr,dc,ci} x[n,r+dr,c+dc,ci] * K[dr,dc,ci,co]),  r,c in [0,504)
//
// Round-2 post-mortem: k scalarized to s_load (good) but x came from LDS, and
// ds_read + s_load share lgkmcnt (SMEM completes out-of-order) -> compiler
// emits lgkmcnt(0) drains every ~64 FMAs; with only 3 waves/SIMD (46.6 KB LDS
// -> 3 blocks/CU) the latency was exposed: VALUBusy 46.6%, dur 734 us.
//
// This version deletes LDS entirely:
//   - x read directly from global as float4 (32-fold in-thread reuse per load,
//     neighbor threads share L1 lines) -> waits on vmcnt, decoupled from the
//     k s_load stream on lgkmcnt
//   - no staging, no barrier, LDS=0 -> occupancy becomes VGPR-bound (~5-6
//     waves/SIMD instead of 3)
//   - k stays wave-uniform -> s_load chunks, FMAs take k from SGPR
//   - bias folded into accumulator init (saves 32 adds in epilogue)

#define NN    8
#define HH    506
#define WW    506
#define CIN   32
#define COUT  32
#define OH    504
#define OW    504
#define NBH   36
#define NBW   36

// ---------------- flag precompute: active[n][bh][bw] ----------------
__global__ __launch_bounds__(256) void mask_flags_kernel(
    const float* __restrict__ mask, float* __restrict__ flags)
{
    __shared__ float sred[4];
    const int bw = blockIdx.x, bh = blockIdx.y, n = blockIdx.z;
    const int t = threadIdx.x;
    const int i = t >> 4, j = t & 15;           // 16x16 window at stride-14 grid
    float m = mask[(size_t)(n * HH + bh * 14 + i) * WW + (bw * 14 + j)];
    #pragma unroll
    for (int off = 32; off > 0; off >>= 1)
        m = fmaxf(m, __shfl_down(m, off, 64));
    if ((t & 63) == 0) sred[t >> 6] = m;
    __syncthreads();
    if (t == 0) {
        const float mm = fmaxf(fmaxf(sred[0], sred[1]), fmaxf(sred[2], sred[3]));
        flags[(n * NBH + bh) * NBW + bw] = (mm > 0.5f) ? 1.0f : 0.0f;
    }
}

// ---------------- main conv: direct-from-global, no LDS ----------------
#define TO 16                    // output tile edge (16x16 = 256 threads)

__global__ __launch_bounds__(256) void conv_direct_kernel(
    const float* __restrict__ x, const float* __restrict__ kern,
    const float* __restrict__ bias, const float* __restrict__ flags,
    float* __restrict__ out)
{
    const int t = threadIdx.x;
    const int i = t >> 4, j = t & 15;
    const int r = blockIdx.y * TO + i;
    const int c = blockIdx.x * TO + j;
    const int n = blockIdx.z;
    // edge tiles (grid is 32x32 of 16, output 504): no barriers in this
    // kernel, so per-thread early-out is safe.  Interior loads then need no
    // clamp: r<=503 -> input rows r..r+2 <= 505 = HH-1.
    if (r >= OH || c >= OW) return;

    // independent load, issued early so its latency hides under the loop
    const float flag = flags[((size_t)n * NBH + (r / 14)) * NBW + (c / 14)];

    // bias is wave-uniform -> s_load; fold into acc init
    float acc[COUT];
    #pragma unroll
    for (int co = 0; co < COUT; ++co) acc[co] = bias[co];

    const float* xb = x + ((size_t)(n * HH + r) * WW + c) * CIN;

    #pragma unroll 1                 // one ~9KB body: fits I$
    for (int dr = 0; dr < 3; ++dr) {
        const float* xr = xb + (size_t)dr * (WW * CIN);
        #pragma unroll 1
        for (int dc = 0; dc < 3; ++dc) {
            // 32 channels of one input position: 8x global_load_dwordx4,
            // contiguous 128 B, consecutive j -> consecutive 128 B lines.
            // These wait on vmcnt; k s_loads below wait on lgkmcnt -> the
            // two streams never force a joint drain.
            const float4* xp = (const float4*)(xr + dc * CIN);
            const float4 v0 = xp[0], v1 = xp[1], v2 = xp[2], v3 = xp[3];
            const float4 v4 = xp[4], v5 = xp[5], v6 = xp[6], v7 = xp[7];
            float xv[CIN];
            xv[ 0]=v0.x; xv[ 1]=v0.y; xv[ 2]=v0.z; xv[ 3]=v0.w;
            xv[ 4]=v1.x; xv[ 5]=v1.y; xv[ 6]=v1.z; xv[ 7]=v1.w;
            xv[ 8]=v2.x; xv[ 9]=v2.y; xv[10]=v2.z; xv[11]=v2.w;
            xv[12]=v3.x; xv[13]=v3.y; xv[14]=v3.z; xv[15]=v3.w;
            xv[16]=v4.x; xv[17]=v4.y; xv[18]=v4.z; xv[19]=v4.w;
            xv[20]=v5.x; xv[21]=v5.y; xv[22]=v5.z; xv[23]=v5.w;
            xv[24]=v6.x; xv[25]=v6.y; xv[26]=v6.z; xv[27]=v6.w;
            xv[28]=v7.x; xv[29]=v7.y; xv[30]=v7.z; xv[31]=v7.w;

            // kern index is thread-invariant -> s_load (scalar cache),
            // FMAs take k from SGPR (one SGPR operand per VALU op: legal).
            const float* kp = kern + (dr * 3 + dc) * (CIN * COUT);
            #pragma unroll
            for (int ci = 0; ci < CIN; ++ci) {
                const float xc = xv[ci];
                #pragma unroll
                for (int co = 0; co < COUT; ++co)
                    acc[co] = fmaf(xc, kp[ci * COUT + co], acc[co]);
            }
        }
    }

    float* op = out + ((size_t)(n * OH + r) * OW + c) * COUT;
    #pragma unroll
    for (int g = 0; g < 8; ++g) {
        float4 v;
        v.x = acc[g * 4 + 0] * flag;
        v.y = acc[g * 4 + 1] * flag;
        v.z = acc[g * 4 + 2] * flag;
        v.w = acc[g * 4 + 3] * flag;
        *(float4*)(op + g * 4) = v;
    }
}

extern "C" void kernel_launch(void* const* d_in, const int* in_sizes, int n_in,
                              void* d_out, int out_size, void* d_ws, size_t ws_size,
                              hipStream_t stream) {
    const float* x    = (const float*)d_in[0];
    const float* mask = (const float*)d_in[1];
    const float* kern = (const float*)d_in[2];
    const float* bias = (const float*)d_in[3];
    float* out        = (float*)d_out;
    float* flags      = (float*)d_ws;          // 8*36*36 floats = 41.5 KB

    dim3 gridA(NBW, NBH, NN);                  // 36 x 36 x 8 tiles
    mask_flags_kernel<<<gridA, 256, 0, stream>>>(mask, flags);

    dim3 gridB((OW + TO - 1) / TO, (OH + TO - 1) / TO, NN);  // 32 x 32 x 8
    conv_direct_kernel<<<gridB, 256, 0, stream>>>(x, kern, bias, flags, out);
}

// Round 6
// 772.624 us; speedup vs baseline: 1.3224x; 1.3224x over previous
//
#include <hip/hip_runtime.h>

// SparseConv2D on MI355X (gfx950), round 4 kernel (2nd resubmit — rounds 4
// and 5 both hit GPU-broker acquisition timeouts; no counters produced).
// Collapsed valid 3x3 conv:
//   out[n,r,c,co] = active[n,r/14,c/14] * (bias[co] +
//       sum_{dr,dc,ci} x[n,r+dr,c+dc,ci] * K[dr,dc,ci,co]),  r,c in [0,504)
//
// Round-3 post-mortem: direct-global x => FETCH_SIZE 2.3 GB (= 9x the x
// tensor, one full HBM pass per conv tap); dur 750us == hbm_bytes/3.1TB/s.
// L1 (32KB < 41.5KB window) and L2 (thrashed) absorb nothing. x MUST be LDS-
// staged (round 2 fetched only 155MB).  Round-2's stall (VALUBusy 46.6%) was
// exposed s_load/ds_read latency at only ~2.7 waves/SIMD (46.6KB LDS -> 3
// blocks/CU).
//
// Fix: split the ci-reduction into two 16-channel phases.  LDS/block drops to
// 25.9KB -> 6 blocks/CU -> 6 waves/SIMD; TLP covers the lgkmcnt stalls.
//   - thread = one output position, 32 co accumulators
//   - x per-lane-distinct from LDS, position stride 20 floats (16 data + 4
//     pad): b128-aligned AND spreads 64 lanes evenly over all 32 banks
//     (stride 16 would hit only 8 banks = 4x LDS slowdown)
//   - k wave-uniform -> s_load chunks, FMA takes k from SGPR
//   - bias folded into acc init; flags precomputed by tiny kernel

#define NN    8
#define HH    506
#define WW    506
#define CIN   32
#define COUT  32
#define OH    504
#define OW    504
#define NBH   36
#define NBW   36

// ---------------- flag precompute: active[n][bh][bw] ----------------
__global__ __launch_bounds__(256) void mask_flags_kernel(
    const float* __restrict__ mask, float* __restrict__ flags)
{
    __shared__ float sred[4];
    const int bw = blockIdx.x, bh = blockIdx.y, n = blockIdx.z;
    const int t = threadIdx.x;
    const int i = t >> 4, j = t & 15;           // 16x16 window at stride-14 grid
    float m = mask[(size_t)(n * HH + bh * 14 + i) * WW + (bw * 14 + j)];
    #pragma unroll
    for (int off = 32; off > 0; off >>= 1)
        m = fmaxf(m, __shfl_down(m, off, 64));
    if ((t & 63) == 0) sred[t >> 6] = m;
    __syncthreads();
    if (t == 0) {
        const float mm = fmaxf(fmaxf(sred[0], sred[1]), fmaxf(sred[2], sred[3]));
        flags[(n * NBH + bh) * NBW + bw] = (mm > 0.5f) ? 1.0f : 0.0f;
    }
}

// ---------------- main conv: 16x16 output tile, 2 ci-phases ----------------
#define TO 16                    // output tile edge (256 threads)
#define TI 18                    // input tile edge
#define PC 16                    // channels per phase
#define PS 20                    // LDS position stride in floats (16 + 4 pad)

__global__ __launch_bounds__(256, 6) void conv16_kernel(
    const float* __restrict__ x, const float* __restrict__ kern,
    const float* __restrict__ bias, const float* __restrict__ flags,
    float* __restrict__ out)
{
    __shared__ float xs[TI * TI * PS];          // 25920 B -> 6 blocks/CU

    const int bx = blockIdx.x, by = blockIdx.y, n = blockIdx.z;
    const int R0 = by * TO, C0 = bx * TO;
    const int t = threadIdx.x;
    const int i = t >> 4, j = t & 15;
    const int r = R0 + i, c = C0 + j;

    // independent scalar-ish loads, issued early
    const float flag = flags[((size_t)n * NBH + (r < OH ? r : OH - 1) / 14) * NBW
                             + (c < OW ? c : OW - 1) / 14];

    float acc[COUT];
    #pragma unroll
    for (int co = 0; co < COUT; ++co) acc[co] = bias[co];

    #pragma unroll 1
    for (int ph = 0; ph < 2; ++ph) {
        if (ph) __syncthreads();                // WAR: phase-0 compute done
        // stage 18x18 positions x 16 channels = 1296 float4, clamped at edges
        for (int q = t; q < TI * TI * 4; q += 256) {
            const int p = q >> 2, g = q & 3;
            const int row = p / TI, col = p - row * TI;
            const int gr = min(R0 + row, HH - 1);   // clamped rows/cols only
            const int gc = min(C0 + col, WW - 1);   // feed discarded outputs
            const float4 v = *(const float4*)(
                x + ((size_t)(n * HH + gr) * WW + gc) * CIN + ph * PC + g * 4);
            *(float4*)&xs[p * PS + g * 4] = v;
        }
        __syncthreads();

        #pragma unroll 1                        // body per tap ~512 FMA
        for (int dr = 0; dr < 3; ++dr) {
            #pragma unroll 1
            for (int dc = 0; dc < 3; ++dc) {
                const float4* xp =
                    (const float4*)&xs[((i + dr) * TI + (j + dc)) * PS];
                const float4 v0 = xp[0], v1 = xp[1], v2 = xp[2], v3 = xp[3];
                float xv[PC];
                xv[ 0]=v0.x; xv[ 1]=v0.y; xv[ 2]=v0.z; xv[ 3]=v0.w;
                xv[ 4]=v1.x; xv[ 5]=v1.y; xv[ 6]=v1.z; xv[ 7]=v1.w;
                xv[ 8]=v2.x; xv[ 9]=v2.y; xv[10]=v2.z; xv[11]=v2.w;
                xv[12]=v3.x; xv[13]=v3.y; xv[14]=v3.z; xv[15]=v3.w;
                // k index thread-invariant -> s_load; FMA k-operand is SGPR
                const float* kp = kern + ((dr * 3 + dc) * CIN + ph * PC) * COUT;
                #pragma unroll
                for (int ci = 0; ci < PC; ++ci) {
                    const float xc = xv[ci];
                    #pragma unroll
                    for (int co = 0; co < COUT; ++co)
                        acc[co] = fmaf(xc, kp[ci * COUT + co], acc[co]);
                }
            }
        }
    }

    if (r < OH && c < OW) {
        float* op = out + ((size_t)(n * OH + r) * OW + c) * COUT;
        #pragma unroll
        for (int g = 0; g < 8; ++g) {
            float4 v;
            v.x = acc[g * 4 + 0] * flag;
            v.y = acc[g * 4 + 1] * flag;
            v.z = acc[g * 4 + 2] * flag;
            v.w = acc[g * 4 + 3] * flag;
            *(float4*)(op + g * 4) = v;
        }
    }
}

extern "C" void kernel_launch(void* const* d_in, const int* in_sizes, int n_in,
                              void* d_out, int out_size, void* d_ws, size_t ws_size,
                              hipStream_t stream) {
    const float* x    = (const float*)d_in[0];
    const float* mask = (const float*)d_in[1];
    const float* kern = (const float*)d_in[2];
    const float* bias = (const float*)d_in[3];
    float* out        = (float*)d_out;
    float* flags      = (float*)d_ws;          // 8*36*36 floats = 41.5 KB

    dim3 gridA(NBW, NBH, NN);                  // 36 x 36 x 8 tiles
    mask_flags_kernel<<<gridA, 256, 0, stream>>>(mask, flags);

    dim3 gridB((OW + TO - 1) / TO, (OH + TO - 1) / TO, NN);  // 32 x 32 x 8
    conv16_kernel<<<gridB, 256, 0, stream>>>(x, kern, bias, flags, out);
}